// Round 3
// baseline (51.489 us; speedup 1.0000x reference)
//
#include <hip/hip_runtime.h>

// LatencyEncoder: out[b, t, n] = (t == floor(clip(-TAU*log(sigmoid(x[b,n])+EPS), 0, T-1))) ? 1 : 0
// B=256, N=4096, T=64. Output 256 MiB fp32 -> write-BW bound.
// R2: non-temporal stores via native clang vector type (HIP_vector_type rejected by builtin).

#define B_DIM 256
#define N_DIM 4096
#define T_DIM 64

typedef float f32x4 __attribute__((ext_vector_type(4)));

__global__ __launch_bounds__(256) void latency_encoder_kernel(
    const float* __restrict__ x, float* __restrict__ out)
{
    const int b  = blockIdx.y;
    const int n0 = (blockIdx.x * 256 + threadIdx.x) * 4;  // 4 consecutive n per thread

    // Load 4 inputs (coalesced 16B/lane, read-once -> non-temporal)
    const f32x4 xv = __builtin_nontemporal_load(
        reinterpret_cast<const f32x4*>(x + (size_t)b * N_DIM + n0));
    const float xs[4] = {xv.x, xv.y, xv.z, xv.w};

    // Compute spike time in double precision so floor() decisions match the
    // float64 numpy reference (f32 transcendental ULP noise near integer
    // boundaries would flip one-hot bins -> absmax 1.0 failure).
    int t[4];
#pragma unroll
    for (int i = 0; i < 4; ++i) {
        const double s   = 1.0 / (1.0 + exp(-(double)xs[i]));
        double lat = -10.0 * log(s + 1e-7);
        lat = lat < 0.0 ? 0.0 : (lat > 63.0 ? 63.0 : lat);
        t[i] = (int)lat;  // lat >= 0, trunc == floor
    }

    // Write the one-hot time series: 64 coalesced 16B streaming stores.
    f32x4* outp = reinterpret_cast<f32x4*>(out + (size_t)b * (T_DIM * N_DIM) + n0);
#pragma unroll
    for (int tt = 0; tt < T_DIM; ++tt) {
        f32x4 v;
        v.x = (tt == t[0]) ? 1.0f : 0.0f;
        v.y = (tt == t[1]) ? 1.0f : 0.0f;
        v.z = (tt == t[2]) ? 1.0f : 0.0f;
        v.w = (tt == t[3]) ? 1.0f : 0.0f;
        __builtin_nontemporal_store(v, outp + (size_t)tt * (N_DIM / 4));
    }
}

extern "C" void kernel_launch(void* const* d_in, const int* in_sizes, int n_in,
                              void* d_out, int out_size, void* d_ws, size_t ws_size,
                              hipStream_t stream)
{
    const float* x = (const float*)d_in[0];
    float* out = (float*)d_out;

    // 4096 n / (256 threads * 4 per thread) = 4 blocks per row, 256 rows.
    dim3 grid(N_DIM / (256 * 4), B_DIM);
    latency_encoder_kernel<<<grid, 256, 0, stream>>>(x, out);
}

// Round 4
// 44.906 us; speedup vs baseline: 1.1466x; 1.1466x over previous
//
#include <hip/hip_runtime.h>

// LatencyEncoder: out[b, t, n] = (t == floor(clip(-TAU*log(sigmoid(x[b,n])+EPS), 0, T-1))) ? 1 : 0
// B=256, N=4096, T=64. Output 256 MiB fp32 -> write-BW bound.
// R3: contiguous-write restructure. Each block owns (b, 16 consecutive t, all n)
//     = one 256 KB fully contiguous output region (like fillBufferAligned's pattern,
//     which hits 7.03 TB/s vs our 6.54). Spike times for the whole row staged in LDS.
//     NT stores reverted (R2: -24%, L2 write-back aggregation matters on gfx950).

#define B_DIM 256
#define N_DIM 4096
#define T_DIM 64
#define CHUNK_T 16   // t-steps per block -> 16*4096*4B = 256 KB contiguous per block

typedef float f32x4 __attribute__((ext_vector_type(4)));

__global__ __launch_bounds__(256) void latency_encoder_kernel(
    const float* __restrict__ x, float* __restrict__ out)
{
    __shared__ uint t_lds[N_DIM / 4];  // spike times packed as uchar4, 4 KB

    const int b   = blockIdx.y;
    const int t0  = blockIdx.x * CHUNK_T;
    const int tid = threadIdx.x;

    // ---- Phase 1: compute t[n] for the entire row b, stage packed in LDS ----
    // Thread handles 4 float4-groups strided by 1024 floats (coalesced loads).
    // Double precision so floor() matches the float64 numpy reference exactly
    // (f32 transcendental ULP noise flips one-hot bins -> absmax 1.0).
#pragma unroll
    for (int j = 0; j < 4; ++j) {
        const int n4 = j * 256 + tid;  // float4 index within row, 0..1023
        const f32x4 xv = *reinterpret_cast<const f32x4*>(x + (size_t)b * N_DIM + n4 * 4);
        uint packed = 0;
#pragma unroll
        for (int i = 0; i < 4; ++i) {
            const double s = 1.0 / (1.0 + exp(-(double)xv[i]));
            double lat = -10.0 * log(s + 1e-7);
            lat = lat < 0.0 ? 0.0 : (lat > 63.0 ? 63.0 : lat);
            packed |= ((uint)(int)lat) << (8 * i);  // lat >= 0, trunc == floor
        }
        t_lds[n4] = packed;
    }
    __syncthreads();

    // ---- Phase 2: stream the 256 KB contiguous output chunk ----
    // 64 iterations x 256 threads x 16B = 16 t-steps x 4096 n. Consecutive lanes
    // write consecutive 16B (1 KB/wave contiguous); block region fully sequential.
    // LDS read: consecutive lanes -> consecutive dwords -> 2 lanes/bank (free).
    f32x4* base4 = reinterpret_cast<f32x4*>(
        out + (size_t)b * (T_DIM * N_DIM) + (size_t)t0 * N_DIM);
#pragma unroll 4
    for (int k = 0; k < 64; ++k) {
        const int idx4 = k * 256 + tid;                 // float4 index in chunk
        const uint tt  = (uint)(t0 + (idx4 >> 10));     // which time step
        const uint u   = t_lds[idx4 & 1023];            // 4 packed spike times
        f32x4 v;
        v.x = ((u         & 255u) == tt) ? 1.0f : 0.0f;
        v.y = (((u >> 8)  & 255u) == tt) ? 1.0f : 0.0f;
        v.z = (((u >> 16) & 255u) == tt) ? 1.0f : 0.0f;
        v.w = ((u >> 24)          == tt) ? 1.0f : 0.0f;
        base4[idx4] = v;
    }
}

extern "C" void kernel_launch(void* const* d_in, const int* in_sizes, int n_in,
                              void* d_out, int out_size, void* d_ws, size_t ws_size,
                              hipStream_t stream)
{
    const float* x = (const float*)d_in[0];
    float* out = (float*)d_out;

    dim3 grid(T_DIM / CHUNK_T, B_DIM);  // (4, 256) = 1024 blocks, 256 KB each
    latency_encoder_kernel<<<grid, 256, 0, stream>>>(x, out);
}

// Round 5
// 40.942 us; speedup vs baseline: 1.2576x; 1.0968x over previous
//
#include <hip/hip_runtime.h>
#include <cmath>

// LatencyEncoder: out[b, t, n] = (t == floor(clip(-TAU*log(sigmoid(x[b,n])+EPS), 0, T-1))) ? 1 : 0
// B=256, N=4096, T=64. Output 256 MiB fp32 -> write-BW bound. Best: R0 structure (41.67us).
// R4: replace per-element f64 exp/log (serial compute prologue, ~1000 cyc/thread) with
//     exact threshold inversion: t >= k  <=>  x <= E_k, E_k = logit(e^{-k/10}-1e-7) computed
//     on HOST in f64, rounded DOWN to f32 (largest f32 <= E_k) so the f32 compare is exactly
//     equivalent to the f64 decision for every f32 x. Device: hw __expf/__logf estimate
//     (error ~3e-5 << bin width 1 -> off by <=1) + exact +-1 fixup from LDS table.
// History: R2 nt stores -24% (keep L2 in write path); R3 contiguous 256KB blocks -8%.

#define B_DIM 256
#define N_DIM 4096
#define T_DIM 64

typedef float f32x4 __attribute__((ext_vector_type(4)));

struct ThreshTab { float c[65]; };  // c[0]=+INF, c[k] k=1..63 decreasing, c[64]=-INF

__global__ __launch_bounds__(256) void latency_encoder_kernel(
    const float* __restrict__ x, float* __restrict__ out, ThreshTab tab)
{
    __shared__ float C[65];
    const int tid = threadIdx.x;
    if (tid < 65) C[tid] = tab.c[tid];
    __syncthreads();

    const int b  = blockIdx.y;
    const int n0 = (blockIdx.x * 256 + tid) * 4;  // 4 consecutive n per thread

    const f32x4 xv = *reinterpret_cast<const f32x4*>(x + (size_t)b * N_DIM + n0);

    int t[4];
#pragma unroll
    for (int i = 0; i < 4; ++i) {
        const float xf = xv[i];
        // Fast f32 estimate (hw exp/log). Worst-case lat error ~3e-5 << 1 -> t off by <=1.
        const float e  = __expf(-xf);            // overflow to +inf ok: s->0, lat->161->clamp
        const float s  = 1.0f / (1.0f + e);
        const float lat = -10.0f * __logf(s + 1e-7f);
        int th = (int)lat;                        // lat >= -1e-5; trunc == floor after clamp
        th = th < 0 ? 0 : (th > 63 ? 63 : th);
        // Exact fixup: invariant for correct t: x <= C[t] (or t==0) and x > C[t+1] (or t==63).
        const float chi = C[th];
        const float clo = C[th + 1];
        th += (xf <= clo) ? 1 : ((xf > chi) ? -1 : 0);
        t[i] = th;
    }

    // Write the one-hot time series: 64 coalesced float4 stores (R0 pattern, best measured).
    f32x4* outp = reinterpret_cast<f32x4*>(out + (size_t)b * (T_DIM * N_DIM) + n0);
#pragma unroll
    for (int tt = 0; tt < T_DIM; ++tt) {
        f32x4 v;
        v.x = (tt == t[0]) ? 1.0f : 0.0f;
        v.y = (tt == t[1]) ? 1.0f : 0.0f;
        v.z = (tt == t[2]) ? 1.0f : 0.0f;
        v.w = (tt == t[3]) ? 1.0f : 0.0f;
        outp[(size_t)tt * (N_DIM / 4)] = v;
    }
}

extern "C" void kernel_launch(void* const* d_in, const int* in_sizes, int n_in,
                              void* d_out, int out_size, void* d_ws, size_t ws_size,
                              hipStream_t stream)
{
    const float* x = (const float*)d_in[0];
    float* out = (float*)d_out;

    // Host-side exact threshold table (deterministic, pure CPU math — graph-capture safe).
    ThreshTab tab;
    tab.c[0]  =  INFINITY;
    tab.c[64] = -INFINITY;
    for (int k = 1; k <= 63; ++k) {
        const double Sk = exp(-(double)k / 10.0) - 1e-7;   // sigmoid threshold, in (0,1)
        const double Ek = log(Sk / (1.0 - Sk));            // x threshold (logit), f64
        float c = (float)Ek;
        if ((double)c > Ek) c = nextafterf(c, -INFINITY);  // largest f32 <= Ek
        tab.c[k] = c;
    }

    dim3 grid(N_DIM / (256 * 4), B_DIM);  // 4 blocks per row, 256 rows
    latency_encoder_kernel<<<grid, 256, 0, stream>>>(x, out, tab);
}